// Round 16
// baseline (149.714 us; speedup 1.0000x reference)
//
#include <hip/hip_runtime.h>

#define B_ 4
#define QN 512
#define KVN 512
#define QD_ 512
#define H_ 256
#define VD_ 256
#define TOTR 2048  // B_*QN

typedef __attribute__((ext_vector_type(8))) short bf16x8;
typedef __attribute__((ext_vector_type(4))) float f32x4;
typedef __attribute__((ext_vector_type(4))) unsigned short u16x4;
typedef unsigned short u16;

__device__ __forceinline__ float rcp_(float x) { return __builtin_amdgcn_rcpf(x); }
__device__ __forceinline__ float ex2_(float x) { return __builtin_amdgcn_exp2f(x); }

__device__ __forceinline__ u16 bf16_rne(float x) {
    unsigned u = __float_as_uint(x);
    unsigned r = u + 0x7FFFu + ((u >> 16) & 1u);
    return (u16)(r >> 16);
}
__device__ __forceinline__ void split2(float x, u16& h, u16& l) {
    h = bf16_rne(x);
    float hf = __uint_as_float((unsigned)h << 16);
    l = bf16_rne(x - hf);
}
__device__ __forceinline__ void split4(float4 a, u16x4& h, u16x4& l) {
    u16 hh, ll;
    split2(a.x, hh, ll); h[0] = hh; l[0] = ll;
    split2(a.y, hh, ll); h[1] = hh; l[1] = ll;
    split2(a.z, hh, ll); h[2] = hh; l[2] = ll;
    split2(a.w, hh, ll); h[3] = hh; l[3] = ll;
}

// ---- prep: presplit (0..2303) + vtrans (2304..2431) + iw table (2432) ------------------
__global__ __launch_bounds__(256) void prep(const float* __restrict__ q,
                                            const float* __restrict__ k,
                                            const float* __restrict__ Wq,
                                            const float* __restrict__ Wk,
                                            const float* __restrict__ v,
                                            const float* __restrict__ wv,
                                            u16* __restrict__ q_hi, u16* __restrict__ q_lo,
                                            u16* __restrict__ k_hi, u16* __restrict__ k_lo,
                                            u16* __restrict__ w_hi, u16* __restrict__ w_lo,
                                            u16* __restrict__ vt_hi, u16* __restrict__ vt_lo,
                                            float* __restrict__ iwg) {
    __shared__ float ts[64][65];
    const int tid = threadIdx.x;
    if (blockIdx.x < 2304) {  // presplit: q,k,Wq,Wk -> bf16 hi/lo planes
        const int NQ = 2048 * 512 / 4, NW = 256 * 512 / 4;
        int idx = blockIdx.x * 256 + tid;
        const float* src; u16 *dh, *dl; int off;
        if (idx < NQ)               { src = q;  dh = q_hi; dl = q_lo; off = idx; }
        else if (idx < 2 * NQ)      { src = k;  dh = k_hi; dl = k_lo; off = idx - NQ; }
        else if (idx < 2 * NQ + NW) { src = Wq; dh = w_hi; dl = w_lo; off = idx - 2 * NQ; }
        else { src = Wk; dh = w_hi + 256 * 512; dl = w_lo + 256 * 512; off = idx - 2 * NQ - NW; }
        float4 v4 = ((const float4*)src)[off];
        u16x4 h, l;
        split4(v4, h, l);
        *(u16x4*)(dh + off * 4) = h;
        *(u16x4*)(dl + off * 4) = l;
    } else if (blockIdx.x < 2432) {  // vtrans: v[b][j][n] -> vt_hi/lo[b][n][j]
        int bid = blockIdx.x - 2304;  // 8 j-tiles x 4 n-tiles x 4 b
        int j0 = (bid & 7) * 64, n0 = ((bid >> 3) & 3) * 64, b = bid >> 5;
#pragma unroll
        for (int t = 0; t < 4; ++t) {
            int idx = t * 256 + tid;
            int j = idx >> 4, nq = idx & 15;
            float4 v4 = *(const float4*)(v + ((size_t)b * KVN + j0 + j) * VD_ + n0 + nq * 4);
            *(float4*)&ts[j][nq * 4] = v4;
        }
        __syncthreads();
#pragma unroll
        for (int t = 0; t < 4; ++t) {
            int idx = t * 256 + tid;
            int jq = idx & 15, n = idx >> 4;
            u16x4 h, l;
            u16 hh, ll;
#pragma unroll
            for (int e = 0; e < 4; ++e) {
                split2(ts[jq * 4 + e][n], hh, ll);
                h[e] = hh; l[e] = ll;
            }
            size_t off = ((size_t)b * VD_ + n0 + n) * KVN + j0 + jq * 4;
            *(u16x4*)(vt_hi + off) = h;
            *(u16x4*)(vt_lo + off) = l;
        }
    } else {  // iw table: iwg[h] = rcp(wv[h])
        iwg[tid] = rcp_(wv[tid]);
    }
}

// ---- proj: z=0 -> eqw[row][h] = exp2(qh')·iw[h];  z=1 -> ekT[h][row] = exp2(kh') -------
__global__ __launch_bounds__(256) void proj_mfma(const u16* __restrict__ q_hi, const u16* __restrict__ q_lo,
                                                 const u16* __restrict__ k_hi, const u16* __restrict__ k_lo,
                                                 const u16* __restrict__ w_hi, const u16* __restrict__ w_lo,
                                                 const float* __restrict__ iwg,
                                                 float* __restrict__ eqw, float* __restrict__ ekT) {
    const int z = blockIdx.z;
    const u16* __restrict__ Ah_g = z ? k_hi : q_hi;
    const u16* __restrict__ Al_g = z ? k_lo : q_lo;
    const u16* __restrict__ Bh_g = w_hi + (size_t)z * H_ * QD_;
    const u16* __restrict__ Bl_g = w_lo + (size_t)z * H_ * QD_;
    __shared__ u16 Ash[4][32][8], Asl[4][32][8], Bsh[4][32][8], Bsl[4][32][8];
    const int tid = threadIdx.x;
    const int wave = tid >> 6, lane = tid & 63;
    const int fl = lane & 15, kg = lane >> 4;
    const int r0 = blockIdx.y * 32, c0 = blockIdx.x * 32;
    const int ar = 16 * (wave & 1), bc = 16 * (wave >> 1);
    const int frow = (tid & 127) >> 2, fkq = tid & 3, fsel = tid >> 7;
    f32x4 acc = {};
    for (int k0 = 0; k0 < QD_; k0 += 32) {
        __syncthreads();
        {
            const u16* as = (fsel ? Al_g : Ah_g) + (size_t)(r0 + frow) * QD_ + k0 + fkq * 8;
            u16* ad = fsel ? &Asl[fkq][frow][0] : &Ash[fkq][frow][0];
            *(uint4*)ad = *(const uint4*)as;
            const u16* bs = (fsel ? Bl_g : Bh_g) + (size_t)(c0 + frow) * QD_ + k0 + fkq * 8;
            u16* bd = fsel ? &Bsl[fkq][frow][0] : &Bsh[fkq][frow][0];
            *(uint4*)bd = *(const uint4*)bs;
        }
        __syncthreads();
        bf16x8 a_h = *(const bf16x8*)&Ash[kg][ar + fl][0];
        bf16x8 a_l = *(const bf16x8*)&Asl[kg][ar + fl][0];
        bf16x8 b_h = *(const bf16x8*)&Bsh[kg][bc + fl][0];
        bf16x8 b_l = *(const bf16x8*)&Bsl[kg][bc + fl][0];
        acc = __builtin_amdgcn_mfma_f32_16x16x32_bf16(a_h, b_h, acc, 0, 0, 0);
        acc = __builtin_amdgcn_mfma_f32_16x16x32_bf16(a_h, b_l, acc, 0, 0, 0);
        acc = __builtin_amdgcn_mfma_f32_16x16x32_bf16(a_l, b_h, acc, 0, 0, 0);
    }
    const float cs = 2.8853900817779268f;  // 2*log2(e)
    const int rg = kg * 4;
    if (z == 1) {
        // ekT[h-col][k-row..k-row+3] — contiguous float4 along global k-rows
        float4 o = {ex2_(acc[0] * cs), ex2_(acc[1] * cs), ex2_(acc[2] * cs), ex2_(acc[3] * cs)};
        *(float4*)(ekT + (size_t)(c0 + bc + fl) * TOTR + r0 + ar + rg) = o;
    } else {
        float iw = iwg[c0 + bc + fl];
#pragma unroll
        for (int r = 0; r < 4; ++r)
            eqw[(size_t)(r0 + ar + rg + r) * H_ + c0 + bc + fl] = ex2_(acc[r] * cs) * iw;
    }
}

// ---- scores_sm v2: fused scores+softmax with explicit ekr ping-pong prefetch -----------
// Block = 4 q-rows x 512 k-cols x 256 h.  Thread = 1 col.  d = fma(ek, eqw, iw);
// quad combine -> 3.25 VALU + 0.25 rcp per eval.  ch loop fully unrolled with A/B
// register double-buffer so chunk ch+1's 16 L2 loads issue before chunk ch's compute
// (R15 counters: VALUBusy 60%, 40% latency gap = unhidden L2 batch at 16 waves/CU).
__device__ __forceinline__ void sc_chunk(const float* __restrict__ eqw,
                                         const float* __restrict__ iwg,
                                         const float ekr[16], int row0, int h0,
                                         float sc[4]) {
    float4 iw4[4];
#pragma unroll
    for (int g = 0; g < 4; ++g) iw4[g] = *(const float4*)(iwg + h0 + 4 * g);
#pragma unroll
    for (int qq = 0; qq < 4; ++qq) {
        const float* ep = eqw + (size_t)(row0 + qq) * H_ + h0;  // wave-uniform -> s_load
        float s = 0.f;
#pragma unroll
        for (int g = 0; g < 4; ++g) {
            float4 e = *(const float4*)(ep + 4 * g);
            float d0 = __builtin_fmaf(ekr[4 * g + 0], e.x, iw4[g].x);
            float d1 = __builtin_fmaf(ekr[4 * g + 1], e.y, iw4[g].y);
            float d2 = __builtin_fmaf(ekr[4 * g + 2], e.z, iw4[g].z);
            float d3 = __builtin_fmaf(ekr[4 * g + 3], e.w, iw4[g].w);
            float ab = d0 * d1, cd = d2 * d3;
            float num = __builtin_fmaf(d0 + d1, cd, (d2 + d3) * ab);
            s = __builtin_fmaf(num, rcp_(ab * cd), s);
        }
        sc[qq] += s;
    }
}

__global__ __launch_bounds__(512, 4) void scores_sm(const float* __restrict__ eqw,
                                                    const float* __restrict__ ekT,
                                                    const float* __restrict__ iwg,
                                                    float* __restrict__ attn,
                                                    u16* __restrict__ at_hi,
                                                    u16* __restrict__ at_lo) {
    const int tid = threadIdx.x;          // 0..511 = k-col
    const int row0 = blockIdx.x * 4;      // global q-row (b merged)
    const int b = row0 >> 9;
    const float* __restrict__ ekcol = ekT + b * KVN + tid;
    float sc[4] = {};
    float ekA[16], ekB[16];
#pragma unroll
    for (int t = 0; t < 16; ++t) ekA[t] = ekcol[(size_t)t * TOTR];  // chunk 0
#pragma unroll
    for (int ch = 0; ch < 16; ch += 2) {
        // prefetch chunk ch+1 into B before computing chunk ch from A
#pragma unroll
        for (int t = 0; t < 16; ++t)
            ekB[t] = ekcol[(size_t)((ch + 1) * 16 + t) * TOTR];
        sc_chunk(eqw, iwg, ekA, row0, ch * 16, sc);
        if (ch + 2 < 16) {
#pragma unroll
            for (int t = 0; t < 16; ++t)
                ekA[t] = ekcol[(size_t)((ch + 2) * 16 + t) * TOTR];
        }
        sc_chunk(eqw, iwg, ekB, row0, (ch + 1) * 16, sc);
    }
    // ---- in-block softmax over 512 cols, 4 rows (no max pass; |2s| <= 2||wv||_1) ----
    __shared__ float red[8][4];
    const int wid = tid >> 6, lane = tid & 63;
    float ev[4];
#pragma unroll
    for (int qq = 0; qq < 4; ++qq)
        ev[qq] = ex2_(sc[qq] * -2.8853900817779268f);  // exp(-2s)
#pragma unroll
    for (int qq = 0; qq < 4; ++qq) {
        float ssum = ev[qq];
#pragma unroll
        for (int d = 1; d < 64; d <<= 1) ssum += __shfl_xor(ssum, d);
        if (lane == 0) red[wid][qq] = ssum;
    }
    __syncthreads();
#pragma unroll
    for (int qq = 0; qq < 4; ++qq) {
        float tot = ((red[0][qq] + red[1][qq]) + (red[2][qq] + red[3][qq])) +
                    ((red[4][qq] + red[5][qq]) + (red[6][qq] + red[7][qq]));
        float a = ev[qq] * rcp_(tot);
        size_t base = (size_t)(row0 + qq) * KVN + tid;
        attn[base] = a;
        u16 h, l;
        split2(a, h, l);
        at_hi[base] = h;
        at_lo[base] = l;
    }
}

// ---------------- out: out[b][i][n] = sum_j attn[b][i][j] * v[b][j][n] ------------------
__global__ __launch_bounds__(256) void out_mfma(const u16* __restrict__ vt_hi, const u16* __restrict__ vt_lo,
                                                const u16* __restrict__ at_hi, const u16* __restrict__ at_lo,
                                                float* __restrict__ out) {
    const int b = blockIdx.z;
    const u16* __restrict__ Ah_g = vt_hi + (size_t)b * VD_ * KVN;
    const u16* __restrict__ Al_g = vt_lo + (size_t)b * VD_ * KVN;
    const u16* __restrict__ Bh_g = at_hi + (size_t)b * QN * KVN;
    const u16* __restrict__ Bl_g = at_lo + (size_t)b * QN * KVN;
    float* __restrict__ outb = out + (size_t)b * QN * VD_;
    __shared__ u16 Ash[4][32][8], Asl[4][32][8], Bsh[4][32][8], Bsl[4][32][8];
    const int tid = threadIdx.x;
    const int wave = tid >> 6, lane = tid & 63;
    const int fl = lane & 15, kg = lane >> 4;
    const int r0 = blockIdx.y * 32;  // n-tile
    const int c0 = blockIdx.x * 32;  // i-tile
    const int ar = 16 * (wave & 1), bc = 16 * (wave >> 1);
    const int frow = (tid & 127) >> 2, fkq = tid & 3, fsel = tid >> 7;
    f32x4 acc = {};
    for (int k0 = 0; k0 < KVN; k0 += 32) {
        __syncthreads();
        {
            const u16* as = (fsel ? Al_g : Ah_g) + (size_t)(r0 + frow) * KVN + k0 + fkq * 8;
            u16* ad = fsel ? &Asl[fkq][frow][0] : &Ash[fkq][frow][0];
            *(uint4*)ad = *(const uint4*)as;
            const u16* bs = (fsel ? Bl_g : Bh_g) + (size_t)(c0 + frow) * KVN + k0 + fkq * 8;
            u16* bd = fsel ? &Bsl[fkq][frow][0] : &Bsh[fkq][frow][0];
            *(uint4*)bd = *(const uint4*)bs;
        }
        __syncthreads();
        bf16x8 a_h = *(const bf16x8*)&Ash[kg][ar + fl][0];
        bf16x8 a_l = *(const bf16x8*)&Asl[kg][ar + fl][0];
        bf16x8 b_h = *(const bf16x8*)&Bsh[kg][bc + fl][0];
        bf16x8 b_l = *(const bf16x8*)&Bsl[kg][bc + fl][0];
        acc = __builtin_amdgcn_mfma_f32_16x16x32_bf16(a_h, b_h, acc, 0, 0, 0);
        acc = __builtin_amdgcn_mfma_f32_16x16x32_bf16(a_h, b_l, acc, 0, 0, 0);
        acc = __builtin_amdgcn_mfma_f32_16x16x32_bf16(a_l, b_h, acc, 0, 0, 0);
    }
    const int rg = kg * 4;
    float4 o = {acc[0], acc[1], acc[2], acc[3]};
    *(float4*)(outb + (size_t)(c0 + bc + fl) * VD_ + r0 + ar + rg) = o;
}

extern "C" void kernel_launch(void* const* d_in, const int* in_sizes, int n_in,
                              void* d_out, int out_size, void* d_ws, size_t ws_size,
                              hipStream_t stream) {
    const float* q  = (const float*)d_in[0];
    const float* k  = (const float*)d_in[1];
    const float* v  = (const float*)d_in[2];
    const float* Wq = (const float*)d_in[3];
    const float* Wk = (const float*)d_in[4];
    const float* wv = (const float*)d_in[5];
    float* out  = (float*)d_out;                   // [B, QN, VD]
    float* attn = out + (size_t)B_ * QN * VD_;     // [B, QN, KVN]

    float* eqw = (float*)d_ws;                     // [2048][H] f32 (= exp2(qh')·iw[h])
    float* ekT = eqw + (size_t)TOTR * H_;          // [H][2048] f32 (= exp2(kh'), transposed)
    float* iwg = ekT + (size_t)H_ * TOTR;          // [256] f32 (rcp(wv))
    u16* q_hi = (u16*)(iwg + 256);                 // [2048][512] u16 each
    u16* q_lo = q_hi + 2048 * 512;
    u16* k_hi = q_lo + 2048 * 512;
    u16* k_lo = k_hi + 2048 * 512;
    u16* w_hi = k_lo + 2048 * 512;                 // [512][512] (Wq rows 0-255, Wk 256-511)
    u16* w_lo = w_hi + 512 * 512;
    u16* vt_hi = w_lo + 512 * 512;                 // [4][256][512]
    u16* vt_lo = vt_hi + (size_t)B_ * VD_ * KVN;
    u16* at_hi = q_hi;                             // alias: q planes dead after proj
    u16* at_lo = q_lo;

    prep<<<2433, 256, 0, stream>>>(q, k, Wq, Wk, v, wv, q_hi, q_lo, k_hi, k_lo,
                                   w_hi, w_lo, vt_hi, vt_lo, iwg);
    proj_mfma<<<dim3(H_ / 32, 2048 / 32, 2), 256, 0, stream>>>(q_hi, q_lo, k_hi, k_lo,
                                                               w_hi, w_lo, iwg, eqw, ekT);
    scores_sm<<<TOTR / 4, 512, 0, stream>>>(eqw, ekT, iwg, attn, at_hi, at_lo);
    out_mfma<<<dim3(QN / 32, VD_ / 32, B_), 256, 0, stream>>>(vt_hi, vt_lo, at_hi, at_lo, out);
}

// Round 17
// 70.780 us; speedup vs baseline: 2.1152x; 2.1152x over previous
//
#include <hip/hip_runtime.h>

#define B_ 4
#define QN 512
#define KVN 512
#define QD_ 512
#define H_ 256
#define VD_ 256
#define TOTR 2048  // B_*QN

typedef __attribute__((ext_vector_type(8))) short bf16x8;
typedef __attribute__((ext_vector_type(4))) float f32x4;
typedef __attribute__((ext_vector_type(2))) float f32x2;
typedef __attribute__((ext_vector_type(4))) unsigned short u16x4;
typedef unsigned short u16;

__device__ __forceinline__ float rcp_(float x) { return __builtin_amdgcn_rcpf(x); }
__device__ __forceinline__ float ex2_(float x) { return __builtin_amdgcn_exp2f(x); }

__device__ __forceinline__ u16 bf16_rne(float x) {
    unsigned u = __float_as_uint(x);
    unsigned r = u + 0x7FFFu + ((u >> 16) & 1u);
    return (u16)(r >> 16);
}
__device__ __forceinline__ void split2(float x, u16& h, u16& l) {
    h = bf16_rne(x);
    float hf = __uint_as_float((unsigned)h << 16);
    l = bf16_rne(x - hf);
}
__device__ __forceinline__ void split4(float4 a, u16x4& h, u16x4& l) {
    u16 hh, ll;
    split2(a.x, hh, ll); h[0] = hh; l[0] = ll;
    split2(a.y, hh, ll); h[1] = hh; l[1] = ll;
    split2(a.z, hh, ll); h[2] = hh; l[2] = ll;
    split2(a.w, hh, ll); h[3] = hh; l[3] = ll;
}

// ---- prep: presplit (0..2303) + vtrans (2304..2431) + iw tables (2432) -----------------
__global__ __launch_bounds__(256) void prep(const float* __restrict__ q,
                                            const float* __restrict__ k,
                                            const float* __restrict__ Wq,
                                            const float* __restrict__ Wk,
                                            const float* __restrict__ v,
                                            const float* __restrict__ wv,
                                            u16* __restrict__ q_hi, u16* __restrict__ q_lo,
                                            u16* __restrict__ k_hi, u16* __restrict__ k_lo,
                                            u16* __restrict__ w_hi, u16* __restrict__ w_lo,
                                            u16* __restrict__ vt_hi, u16* __restrict__ vt_lo,
                                            float* __restrict__ iwg,
                                            float2* __restrict__ iwp) {
    __shared__ float ts[64][65];
    const int tid = threadIdx.x;
    if (blockIdx.x < 2304) {  // presplit: q,k,Wq,Wk -> bf16 hi/lo planes
        const int NQ = 2048 * 512 / 4, NW = 256 * 512 / 4;
        int idx = blockIdx.x * 256 + tid;
        const float* src; u16 *dh, *dl; int off;
        if (idx < NQ)               { src = q;  dh = q_hi; dl = q_lo; off = idx; }
        else if (idx < 2 * NQ)      { src = k;  dh = k_hi; dl = k_lo; off = idx - NQ; }
        else if (idx < 2 * NQ + NW) { src = Wq; dh = w_hi; dl = w_lo; off = idx - 2 * NQ; }
        else { src = Wk; dh = w_hi + 256 * 512; dl = w_lo + 256 * 512; off = idx - 2 * NQ - NW; }
        float4 v4 = ((const float4*)src)[off];
        u16x4 h, l;
        split4(v4, h, l);
        *(u16x4*)(dh + off * 4) = h;
        *(u16x4*)(dl + off * 4) = l;
    } else if (blockIdx.x < 2432) {  // vtrans: v[b][j][n] -> vt_hi/lo[b][n][j]
        int bid = blockIdx.x - 2304;  // 8 j-tiles x 4 n-tiles x 4 b
        int j0 = (bid & 7) * 64, n0 = ((bid >> 3) & 3) * 64, b = bid >> 5;
#pragma unroll
        for (int t = 0; t < 4; ++t) {
            int idx = t * 256 + tid;
            int j = idx >> 4, nq = idx & 15;
            float4 v4 = *(const float4*)(v + ((size_t)b * KVN + j0 + j) * VD_ + n0 + nq * 4);
            *(float4*)&ts[j][nq * 4] = v4;
        }
        __syncthreads();
#pragma unroll
        for (int t = 0; t < 4; ++t) {
            int idx = t * 256 + tid;
            int jq = idx & 15, n = idx >> 4;
            u16x4 h, l;
            u16 hh, ll;
#pragma unroll
            for (int e = 0; e < 4; ++e) {
                split2(ts[jq * 4 + e][n], hh, ll);
                h[e] = hh; l[e] = ll;
            }
            size_t off = ((size_t)b * VD_ + n0 + n) * KVN + j0 + jq * 4;
            *(u16x4*)(vt_hi + off) = h;
            *(u16x4*)(vt_lo + off) = l;
        }
    } else {  // iw tables: iwg[h] = rcp(wv[h]); iwp[h] = {iw, iw} (packed dup)
        float r = rcp_(wv[tid]);
        iwg[tid] = r;
        float2 p; p.x = r; p.y = r;
        iwp[tid] = p;
    }
}

// ---- proj: z=0 -> eqw[row][h] = exp2(qh')·iw[h];  z=1 -> ekT[h][row] = exp2(kh') -------
__global__ __launch_bounds__(256) void proj_mfma(const u16* __restrict__ q_hi, const u16* __restrict__ q_lo,
                                                 const u16* __restrict__ k_hi, const u16* __restrict__ k_lo,
                                                 const u16* __restrict__ w_hi, const u16* __restrict__ w_lo,
                                                 const float* __restrict__ iwg,
                                                 float* __restrict__ eqw, float* __restrict__ ekT) {
    const int z = blockIdx.z;
    const u16* __restrict__ Ah_g = z ? k_hi : q_hi;
    const u16* __restrict__ Al_g = z ? k_lo : q_lo;
    const u16* __restrict__ Bh_g = w_hi + (size_t)z * H_ * QD_;
    const u16* __restrict__ Bl_g = w_lo + (size_t)z * H_ * QD_;
    __shared__ u16 Ash[4][32][8], Asl[4][32][8], Bsh[4][32][8], Bsl[4][32][8];
    const int tid = threadIdx.x;
    const int wave = tid >> 6, lane = tid & 63;
    const int fl = lane & 15, kg = lane >> 4;
    const int r0 = blockIdx.y * 32, c0 = blockIdx.x * 32;
    const int ar = 16 * (wave & 1), bc = 16 * (wave >> 1);
    const int frow = (tid & 127) >> 2, fkq = tid & 3, fsel = tid >> 7;
    f32x4 acc = {};
    for (int k0 = 0; k0 < QD_; k0 += 32) {
        __syncthreads();
        {
            const u16* as = (fsel ? Al_g : Ah_g) + (size_t)(r0 + frow) * QD_ + k0 + fkq * 8;
            u16* ad = fsel ? &Asl[fkq][frow][0] : &Ash[fkq][frow][0];
            *(uint4*)ad = *(const uint4*)as;
            const u16* bs = (fsel ? Bl_g : Bh_g) + (size_t)(c0 + frow) * QD_ + k0 + fkq * 8;
            u16* bd = fsel ? &Bsl[fkq][frow][0] : &Bsh[fkq][frow][0];
            *(uint4*)bd = *(const uint4*)bs;
        }
        __syncthreads();
        bf16x8 a_h = *(const bf16x8*)&Ash[kg][ar + fl][0];
        bf16x8 a_l = *(const bf16x8*)&Asl[kg][ar + fl][0];
        bf16x8 b_h = *(const bf16x8*)&Bsh[kg][bc + fl][0];
        bf16x8 b_l = *(const bf16x8*)&Bsl[kg][bc + fl][0];
        acc = __builtin_amdgcn_mfma_f32_16x16x32_bf16(a_h, b_h, acc, 0, 0, 0);
        acc = __builtin_amdgcn_mfma_f32_16x16x32_bf16(a_h, b_l, acc, 0, 0, 0);
        acc = __builtin_amdgcn_mfma_f32_16x16x32_bf16(a_l, b_h, acc, 0, 0, 0);
    }
    const float cs = 2.8853900817779268f;  // 2*log2(e)
    const int rg = kg * 4;
    if (z == 1) {
        // ekT[h-col][k-row..k-row+3] — contiguous float4 along global k-rows
        float4 o = {ex2_(acc[0] * cs), ex2_(acc[1] * cs), ex2_(acc[2] * cs), ex2_(acc[3] * cs)};
        *(float4*)(ekT + (size_t)(c0 + bc + fl) * TOTR + r0 + ar + rg) = o;
    } else {
        float iw = iwg[c0 + bc + fl];
#pragma unroll
        for (int r = 0; r < 4; ++r)
            eqw[(size_t)(r0 + ar + rg + r) * H_ + c0 + bc + fl] = ex2_(acc[r] * cs) * iw;
    }
}

// ---- scores_sm v3: fused scores+softmax, packed f32 over k-col pairs -------------------
// Thread owns 2 adjacent cols.  d = pk_fma(ekp, eq_sgpr_bcast, iwp) = (1+eq·ek)·iw;
// packed quad combine: 12 pk + 2 rcp per 8 evals = 1.5 pk + 0.25 trans/eval (vs R15
// scalar 3 VALU + 0.25).  Chunk = 8 h, natural loop (no manual ping-pong — R16's
// hoisted 32-float buffers spilled: FETCH 263MB of scratch traffic).
__device__ __forceinline__ f32x2 quad_pk(const f32x2* ekp, const f32x2* iw2,
                                         float ea, float eb, float ec, float ed,
                                         int base, f32x2 acc) {
    f32x2 d0 = __builtin_elementwise_fma(ekp[base + 0], (f32x2){ea, ea}, iw2[base + 0]);
    f32x2 d1 = __builtin_elementwise_fma(ekp[base + 1], (f32x2){eb, eb}, iw2[base + 1]);
    f32x2 d2 = __builtin_elementwise_fma(ekp[base + 2], (f32x2){ec, ec}, iw2[base + 2]);
    f32x2 d3 = __builtin_elementwise_fma(ekp[base + 3], (f32x2){ed, ed}, iw2[base + 3]);
    f32x2 ab = d0 * d1, cd = d2 * d3;
    f32x2 num = __builtin_elementwise_fma(d0 + d1, cd, (d2 + d3) * ab);
    f32x2 den = ab * cd;
    f32x2 r = {rcp_(den.x), rcp_(den.y)};
    return __builtin_elementwise_fma(num, r, acc);
}

__global__ __launch_bounds__(256, 4) void scores_sm(const float* __restrict__ eqw,
                                                    const float* __restrict__ ekT,
                                                    const float2* __restrict__ iwp,
                                                    float* __restrict__ attn,
                                                    u16* __restrict__ at_hi,
                                                    u16* __restrict__ at_lo) {
    const int tid = threadIdx.x;          // col-pair index: cols 2tid, 2tid+1
    const int row0 = blockIdx.x * 2;      // 2 q-rows per block (b merged)
    const int b = row0 >> 9;
    const float* __restrict__ ekcol = ekT + b * KVN + 2 * tid;
    f32x2 sc0 = {0.f, 0.f}, sc1 = {0.f, 0.f};
    for (int ch = 0; ch < 32; ++ch) {     // h chunks of 8
        const int h0 = ch * 8;
        f32x2 ekp[8], iw2[8];
#pragma unroll
        for (int t = 0; t < 8; ++t) {
            ekp[t] = *(const f32x2*)(ekcol + (size_t)(h0 + t) * TOTR);  // coalesced b64
            float2 w = iwp[h0 + t];
            iw2[t].x = w.x; iw2[t].y = w.y;
        }
        const float* ep0 = eqw + (size_t)row0 * H_ + h0;  // wave-uniform -> s_load
        const float* ep1 = ep0 + H_;
#pragma unroll
        for (int g = 0; g < 2; ++g) {
            float4 e0 = *(const float4*)(ep0 + 4 * g);
            float4 e1 = *(const float4*)(ep1 + 4 * g);
            sc0 = quad_pk(ekp, iw2, e0.x, e0.y, e0.z, e0.w, 4 * g, sc0);
            sc1 = quad_pk(ekp, iw2, e1.x, e1.y, e1.z, e1.w, 4 * g, sc1);
        }
    }
    // ---- in-block softmax over 512 cols, 2 rows (no max pass; |2s| <= 2||wv||_1) ----
    __shared__ float red[4][2];
    const int wid = tid >> 6, lane = tid & 63;
    const float cexp = -2.8853900817779268f;  // -2*log2(e)
    f32x2 ev0 = {ex2_(sc0.x * cexp), ex2_(sc0.y * cexp)};
    f32x2 ev1 = {ex2_(sc1.x * cexp), ex2_(sc1.y * cexp)};
    float s0 = ev0.x + ev0.y, s1 = ev1.x + ev1.y;
#pragma unroll
    for (int d = 1; d < 64; d <<= 1) {
        s0 += __shfl_xor(s0, d);
        s1 += __shfl_xor(s1, d);
    }
    if (lane == 0) { red[wid][0] = s0; red[wid][1] = s1; }
    __syncthreads();
    float i0 = rcp_(red[0][0] + red[1][0] + red[2][0] + red[3][0]);
    float i1 = rcp_(red[0][1] + red[1][1] + red[2][1] + red[3][1]);
    size_t base0 = (size_t)row0 * KVN + 2 * tid;
    size_t base1 = base0 + KVN;
    f32x2 a0 = {ev0.x * i0, ev0.y * i0};
    f32x2 a1 = {ev1.x * i1, ev1.y * i1};
    *(f32x2*)(attn + base0) = a0;
    *(f32x2*)(attn + base1) = a1;
    u16 h0v, l0v, h1v, l1v;
    split2(a0.x, h0v, l0v); split2(a0.y, h1v, l1v);
    *(uint*)(at_hi + base0) = (uint)h0v | ((uint)h1v << 16);
    *(uint*)(at_lo + base0) = (uint)l0v | ((uint)l1v << 16);
    split2(a1.x, h0v, l0v); split2(a1.y, h1v, l1v);
    *(uint*)(at_hi + base1) = (uint)h0v | ((uint)h1v << 16);
    *(uint*)(at_lo + base1) = (uint)l0v | ((uint)l1v << 16);
}

// ---------------- out: out[b][i][n] = sum_j attn[b][i][j] * v[b][j][n] ------------------
__global__ __launch_bounds__(256) void out_mfma(const u16* __restrict__ vt_hi, const u16* __restrict__ vt_lo,
                                                const u16* __restrict__ at_hi, const u16* __restrict__ at_lo,
                                                float* __restrict__ out) {
    const int b = blockIdx.z;
    const u16* __restrict__ Ah_g = vt_hi + (size_t)b * VD_ * KVN;
    const u16* __restrict__ Al_g = vt_lo + (size_t)b * VD_ * KVN;
    const u16* __restrict__ Bh_g = at_hi + (size_t)b * QN * KVN;
    const u16* __restrict__ Bl_g = at_lo + (size_t)b * QN * KVN;
    float* __restrict__ outb = out + (size_t)b * QN * VD_;
    __shared__ u16 Ash[4][32][8], Asl[4][32][8], Bsh[4][32][8], Bsl[4][32][8];
    const int tid = threadIdx.x;
    const int wave = tid >> 6, lane = tid & 63;
    const int fl = lane & 15, kg = lane >> 4;
    const int r0 = blockIdx.y * 32;  // n-tile
    const int c0 = blockIdx.x * 32;  // i-tile
    const int ar = 16 * (wave & 1), bc = 16 * (wave >> 1);
    const int frow = (tid & 127) >> 2, fkq = tid & 3, fsel = tid >> 7;
    f32x4 acc = {};
    for (int k0 = 0; k0 < KVN; k0 += 32) {
        __syncthreads();
        {
            const u16* as = (fsel ? Al_g : Ah_g) + (size_t)(r0 + frow) * KVN + k0 + fkq * 8;
            u16* ad = fsel ? &Asl[fkq][frow][0] : &Ash[fkq][frow][0];
            *(uint4*)ad = *(const uint4*)as;
            const u16* bs = (fsel ? Bl_g : Bh_g) + (size_t)(c0 + frow) * KVN + k0 + fkq * 8;
            u16* bd = fsel ? &Bsl[fkq][frow][0] : &Bsh[fkq][frow][0];
            *(uint4*)bd = *(const uint4*)bs;
        }
        __syncthreads();
        bf16x8 a_h = *(const bf16x8*)&Ash[kg][ar + fl][0];
        bf16x8 a_l = *(const bf16x8*)&Asl[kg][ar + fl][0];
        bf16x8 b_h = *(const bf16x8*)&Bsh[kg][bc + fl][0];
        bf16x8 b_l = *(const bf16x8*)&Bsl[kg][bc + fl][0];
        acc = __builtin_amdgcn_mfma_f32_16x16x32_bf16(a_h, b_h, acc, 0, 0, 0);
        acc = __builtin_amdgcn_mfma_f32_16x16x32_bf16(a_h, b_l, acc, 0, 0, 0);
        acc = __builtin_amdgcn_mfma_f32_16x16x32_bf16(a_l, b_h, acc, 0, 0, 0);
    }
    const int rg = kg * 4;
    float4 o = {acc[0], acc[1], acc[2], acc[3]};
    *(float4*)(outb + (size_t)(c0 + bc + fl) * VD_ + r0 + ar + rg) = o;
}

extern "C" void kernel_launch(void* const* d_in, const int* in_sizes, int n_in,
                              void* d_out, int out_size, void* d_ws, size_t ws_size,
                              hipStream_t stream) {
    const float* q  = (const float*)d_in[0];
    const float* k  = (const float*)d_in[1];
    const float* v  = (const float*)d_in[2];
    const float* Wq = (const float*)d_in[3];
    const float* Wk = (const float*)d_in[4];
    const float* wv = (const float*)d_in[5];
    float* out  = (float*)d_out;                   // [B, QN, VD]
    float* attn = out + (size_t)B_ * QN * VD_;     // [B, QN, KVN]

    float* eqw = (float*)d_ws;                     // [2048][H] f32 (= exp2(qh')·iw[h])
    float* ekT = eqw + (size_t)TOTR * H_;          // [H][2048] f32 (= exp2(kh'), transposed)
    float* iwg = ekT + (size_t)H_ * TOTR;          // [256] f32 (rcp(wv))
    float2* iwp = (float2*)(iwg + 256);            // [256] f32x2 (dup pairs)
    u16* q_hi = (u16*)(iwp + 256);                 // [2048][512] u16 each
    u16* q_lo = q_hi + 2048 * 512;
    u16* k_hi = q_lo + 2048 * 512;
    u16* k_lo = k_hi + 2048 * 512;
    u16* w_hi = k_lo + 2048 * 512;                 // [512][512] (Wq rows 0-255, Wk 256-511)
    u16* w_lo = w_hi + 512 * 512;
    u16* vt_hi = w_lo + 512 * 512;                 // [4][256][512]
    u16* vt_lo = vt_hi + (size_t)B_ * VD_ * KVN;
    u16* at_hi = q_hi;                             // alias: q planes dead after proj
    u16* at_lo = q_lo;

    prep<<<2433, 256, 0, stream>>>(q, k, Wq, Wk, v, wv, q_hi, q_lo, k_hi, k_lo,
                                   w_hi, w_lo, vt_hi, vt_lo, iwg, iwp);
    proj_mfma<<<dim3(H_ / 32, 2048 / 32, 2), 256, 0, stream>>>(q_hi, q_lo, k_hi, k_lo,
                                                               w_hi, w_lo, iwg, eqw, ekT);
    scores_sm<<<TOTR / 2, 256, 0, stream>>>(eqw, ekT, iwp, attn, at_hi, at_lo);
    out_mfma<<<dim3(QN / 32, VD_ / 32, B_), 256, 0, stream>>>(vt_hi, vt_lo, at_hi, at_lo, out);
}